// Round 18
// baseline (101.398 us; speedup 1.0000x reference)
//
#include <hip/hip_runtime.h>

// Problem constants: B=32, L=2, F=65536, D=768
#define BB 32
#define LL 2
#define FF 65536
#define DD 768
#define F4 (FF / 4)        // 16384 float4 per f row
#define LD (LL * DD)       // 1536
#define BL (BB * LD)       // 49152 outputs

#define NSTEPS (FF / 16)   // 4096 K16-steps
#define APREP_BYTES ((size_t)NSTEPS * 64 * 16)      // 4 MB
#define CHUNK_BYTES ((size_t)BL * sizeof(float))    // 196608 B
#define NF 64              // F-chunks (split-K)
#define KS (NSTEPS / NF)   // 64 K16-steps per chunk

typedef __attribute__((ext_vector_type(8)))  short short8;   // 8 bf16 (4 VGPR)
typedef __attribute__((ext_vector_type(16))) float float16;  // 16 fp32 acc

// fp32 -> bf16 round-to-nearest-even (finite inputs)
static __device__ __forceinline__ unsigned bf16rne(float x)
{
    unsigned u = __float_as_uint(x);
    return (u + 0x7fffu + ((u >> 16) & 1u)) >> 16;
}
static __device__ __forceinline__ unsigned packbf(float a, float b)
{
    return bf16rne(a) | (bf16rne(b) << 16);
}

// Prep: build A-fragments. aprep[s][lane] (uint4) = 8 bf16 of
// A[row = lane&31][k = s*16 + (lane>>5)*8 + j], j=0..7, A[b][k] = f[b][k].
__global__ __launch_bounds__(256) void cc_prep_a(
    const float4* __restrict__ f4,     // [32][16384]
    uint4* __restrict__ aprep)         // [4096][64]
{
    int t = blockIdx.x * 256 + threadIdx.x;      // 0 .. 4096*64-1
    if (t >= NSTEPS * 64) return;
    int s = t >> 6;
    int l = t & 63;
    int b = l & 31;
    int k0 = s * 16 + ((l >> 5) << 3);           // multiple of 8
    float4 fa = f4[(size_t)b * F4 + (k0 >> 2)];
    float4 fb = f4[(size_t)b * F4 + (k0 >> 2) + 1];
    uint4 u;
    u.x = packbf(fa.x, fa.y);
    u.y = packbf(fa.z, fa.w);
    u.z = packbf(fb.x, fb.y);
    u.w = packbf(fb.z, fb.w);
    aprep[t] = u;
}

// Stage 1: MFMA partial GEMM. grid = (48, NF); block = 64 (one wave).
// Wave tile: M=32 (all batches) x N=32, K-chunk = KS*16 = 1024.
// Per K16-step: 1 dwordx4 A-frag + 8 dword weight loads (each two aligned
// 128B lines) + 8 bf16 packs + 1 mfma_32x32x16_bf16.  acc 16 VGPR ->
// ~70 total; (64,4) cap 128 (proven spill-free class). 3072 waves = 3/SIMD.
// C/D layout: col = lane&31, row = (r&3) + 8*(r>>2) + 4*(lane>>5).
__global__ __launch_bounds__(64, 4) void cc_mfma(
    const uint4* __restrict__ aprep,   // [4096][64]
    const float* __restrict__ weight,  // [2][65536][768]
    float* __restrict__ partials)      // [NF][32][1536]
{
    const int lane = threadIdx.x;
    const int ct   = blockIdx.x;       // 0..47 -> 32-wide d-tile
    const int c    = blockIdx.y;       // 0..NF-1
    const int nd0  = ct * 32;
    const int l    = nd0 / DD;
    const int d0   = nd0 - l * DD;

    const int col  = lane & 31;
    const int krow = (lane >> 5) << 3; // 0 or 8

    const float* __restrict__ wbase =
        weight + (size_t)l * FF * DD + d0 + col;

    float16 acc;
#pragma unroll
    for (int i = 0; i < 16; ++i) acc[i] = 0.f;

    const int s0 = c * KS;
    for (int s = s0; s < s0 + KS; ++s) {
        uint4 av = aprep[(size_t)s * 64 + lane];
        short8 a8 = __builtin_bit_cast(short8, av);

        const float* __restrict__ wr = wbase + (size_t)(s * 16 + krow) * DD;
        float wv[8];
#pragma unroll
        for (int j = 0; j < 8; ++j)
            wv[j] = wr[j * DD];
        short8 b8;
#pragma unroll
        for (int jj = 0; jj < 4; ++jj) {
            b8[2 * jj]     = (short)bf16rne(wv[2 * jj]);
            b8[2 * jj + 1] = (short)bf16rne(wv[2 * jj + 1]);
        }
        acc = __builtin_amdgcn_mfma_f32_32x32x16_bf16(a8, b8, acc, 0, 0, 0);
    }

    float* __restrict__ pp =
        partials + (size_t)c * BL + (size_t)(l * DD + d0 + col);
#pragma unroll
    for (int r = 0; r < 16; ++r) {
        int b = (r & 3) + 8 * (r >> 2) + 4 * (lane >> 5);
        pp[(size_t)b * LD] = acc[r];
    }
}

// Stage 2 (fused): out[o] = bias[ld] + sum_c partials[c][o]
__global__ __launch_bounds__(256) void cc_stage2(
    const float* __restrict__ partials,
    const float* __restrict__ bias,
    float* __restrict__ out)
{
    int o = blockIdx.x * 256 + threadIdx.x;   // 0 .. BL-1
    if (o >= BL) return;
    int b  = o / LD;
    int ld = o - b * LD;
    float s = bias[ld];
    const float* __restrict__ p = partials + o;
#pragma unroll 16
    for (int c = 0; c < NF; ++c, p += BL)
        s += *p;
    out[o] = s;
}

// Correctness-only fallback if workspace is too small (fp32 path).
__global__ __launch_bounds__(256) void cc_direct(
    const float* __restrict__ f,
    const float* __restrict__ weight,
    const float* __restrict__ bias,
    float* __restrict__ out)
{
    int o = blockIdx.x * 256 + threadIdx.x;
    if (o >= BL) return;
    int b  = o / LD;
    int ld = o - b * LD;
    int l  = ld / DD;
    int d  = ld - l * DD;
    float s = bias[ld];
    const float* wp = weight + (size_t)l * FF * DD + d;
    const float* fp = f + (size_t)b * FF;
    for (int fi = 0; fi < FF; ++fi)
        s = fmaf(fp[fi], wp[(size_t)fi * DD], s);
    out[o] = s;
}

extern "C" void kernel_launch(void* const* d_in, const int* in_sizes, int n_in,
                              void* d_out, int out_size, void* d_ws, size_t ws_size,
                              hipStream_t stream)
{
    const float* f      = (const float*)d_in[0];   // 32 x 65536
    const float* weight = (const float*)d_in[1];   // 2 x 65536 x 768
    const float* bias   = (const float*)d_in[2];   // 2 x 768
    float* out          = (float*)d_out;           // 32 x 2 x 768

    const size_t need = APREP_BYTES + (size_t)NF * CHUNK_BYTES;
    if (ws_size < need) {
        cc_direct<<<(BL + 255) / 256, 256, 0, stream>>>(f, weight, bias, out);
        return;
    }

    uint4* aprep    = (uint4*)d_ws;
    float* partials = (float*)((char*)d_ws + APREP_BYTES);

    cc_prep_a<<<(NSTEPS * 64 + 255) / 256, 256, 0, stream>>>(
        (const float4*)f, aprep);

    dim3 grid1(48, NF);
    cc_mfma<<<grid1, 64, 0, stream>>>(aprep, weight, partials);

    cc_stage2<<<(BL + 255) / 256, 256, 0, stream>>>(partials, bias, out);
}